// Round 8
// baseline (5912.280 us; speedup 1.0000x reference)
//
#include <hip/hip_runtime.h>
#include <cstdint>
#include <math.h>

// GREEN since r6; r7 = 1783us. Locked-in: PRNG = partitionable threefry
// (key_t = tf((0,42),(0,t)) stacked; bits = o0^o1 of tf(key_t,(0,2s+cat)));
// f32 in/out; out = [4096*144 samples][4096 logP]; decisions proven robust to
// arithmetic (r2 butterfly-f32 / r3 f64 / r4 cr-f32 -> bit-identical streams;
// r7 native f32+rcp -> absmax 0.0).
// r7 post-mortem: VGPR hit the 256 cap -> allocator spilled to memory scratch
// (WRITE_SIZE 68MB = spills, not out) and grid gave 1 wave/SIMD (Occ 11.9) ->
// VALUBusy 41%. This round: CPB=2 (live set ~225, no spill; 2048 waves = 2/SIMD)
// + butterfly dense h@Wd via __shfl_xor (replaces 512 redundant FMA + 96 LDS
// reads per step; butterfly rounding proven safe by r2-vs-r4 evidence).

#define NSAMP 4096
#define NSTEP 144
#define HID 64
#define CPB 2            // chains per block (one wave)

typedef float v16f __attribute__((ext_vector_type(16)));

// ---- JAX threefry2x32 (20 rounds, key-inject every 4) ----
__device__ __forceinline__ void threefry2x32(uint32_t k0, uint32_t k1,
                                             uint32_t x0, uint32_t x1,
                                             uint32_t& o0, uint32_t& o1) {
  const uint32_t ks0 = k0, ks1 = k1, ks2 = k0 ^ k1 ^ 0x1BD11BDAu;
  x0 += ks0; x1 += ks1;
#define TF_ROUND(d) { x0 += x1; x1 = (x1 << (d)) | (x1 >> (32 - (d))); x1 ^= x0; }
  TF_ROUND(13) TF_ROUND(15) TF_ROUND(26) TF_ROUND(6)
  x0 += ks1; x1 += ks2 + 1u;
  TF_ROUND(17) TF_ROUND(29) TF_ROUND(16) TF_ROUND(24)
  x0 += ks2; x1 += ks0 + 2u;
  TF_ROUND(13) TF_ROUND(15) TF_ROUND(26) TF_ROUND(6)
  x0 += ks0; x1 += ks1 + 3u;
  TF_ROUND(17) TF_ROUND(29) TF_ROUND(16) TF_ROUND(24)
  x0 += ks1; x1 += ks2 + 4u;
  TF_ROUND(13) TF_ROUND(15) TF_ROUND(26) TF_ROUND(6)
  x0 += ks2; x1 += ks0 + 5u;
#undef TF_ROUND
  o0 = x0; o1 = x1;
}

__global__ __launch_bounds__(64, 2) void vmc_kernel(
    const float* __restrict__ W, const float* __restrict__ U,
    const float* __restrict__ B, const float* __restrict__ Wd,
    const float* __restrict__ Bd, float* __restrict__ out) {
#pragma clang fp contract(off)
  const int j = threadIdx.x;           // hidden unit owned by this lane
  const int s_base = blockIdx.x * CPB; // first of 2 chains in this block

  __shared__ __align__(16) float2 hsh2[HID];   // h[unit] = {chain a, chain b}
  __shared__ uint2 kkeys[NSTEP];
  __shared__ float gsh[CPB * 2 * NSTEP];       // gumbels [c*288 + 2t + cat]

  // --- per-step keys: key_t = threefry((0,42),(0,t)) ---
#pragma unroll
  for (int k = 0; k < 3; ++k) {
    const int t = j + 64 * k;
    if (t < NSTEP) {
      uint32_t o0, o1;
      threefry2x32(0u, 42u, 0u, (uint32_t)t, o0, o1);
      kkeys[t].x = o0; kkeys[t].y = o1;
    }
  }
  hsh2[j] = float2{0.0f, 0.0f};
  __syncthreads();

  // --- gumbels: 2 chains x 288 draws; bits = o0^o1 of tf(key_t,(0,2s+cat)) ---
#pragma unroll
  for (int k = 0; k < 9; ++k) {
    const int id = j + 64 * k;              // 0..575 = c*288 + idx
    const int c = id / 288;
    const int idx = id - c * 288;
    const uint2 kt = kkeys[idx >> 1];
    const uint32_t i = 2u * (uint32_t)(s_base + c) + (uint32_t)(idx & 1);
    uint32_t o0, o1;
    threefry2x32(kt.x, kt.y, 0u, i, o0, o1);
    const uint32_t bits = o0 ^ o1;
    union { uint32_t u; float f; } cv; cv.u = (bits >> 9) | 0x3F800000u;
    float uf = cv.f - 1.0f;
    uf = fmaxf(uf, 1.17549435e-38f);
    const float inner = logf(uf);
    gsh[id] = -logf(-inner);
  }
  __syncthreads();

  // --- U columns for unit j, register-resident as named SSA vectors ---
  v16f uz0, uz1, uz2, uz3, ur0, ur1, ur2, ur3, un0, un1, un2, un3;
#define LOADB(v, r, off) \
  { _Pragma("unroll") for (int e = 0; e < 16; ++e) v[e] = U[((r)*16 + e)*192 + (off) + j]; }
  LOADB(uz0, 0, 0)   LOADB(uz1, 1, 0)   LOADB(uz2, 2, 0)   LOADB(uz3, 3, 0)
  LOADB(ur0, 0, 64)  LOADB(ur1, 1, 64)  LOADB(ur2, 2, 64)  LOADB(ur3, 3, 64)
  LOADB(un0, 0, 128) LOADB(un1, 1, 128) LOADB(un2, 2, 128) LOADB(un3, 3, 128)
#undef LOADB

  const float b1z = B[192 + j], b1r = B[256 + j], b1n = B[320 + j];
  const float b0z = B[j],       b0r = B[64 + j],  b0n = B[128 + j];
  const float xW0z = W[j]       + b0z, xW1z = W[192 + j] + b0z;
  const float xW0r = W[64 + j]  + b0r, xW1r = W[256 + j] + b0r;
  const float xW0n = W[128 + j] + b0n, xW1n = W[320 + j] + b0n;
  const float wd0 = Wd[2*j], wd1 = Wd[2*j + 1];
  const float bd0 = Bd[0],   bd1 = Bd[1];

  float ha = 0.0f, hb_ = 0.0f;          // h for chain a / b (unit j)
  float logPa = 0.0f, logPb = 0.0f;
  float axz = b0z, axr = b0r, axn = b0n;  // chain a x-path (t=0: x=0 -> b[0])
  float bxz = b0z, bxr = b0r, bxn = b0n;  // chain b

  for (int t = 0; t < NSTEP; ++t) {
    // ---- hm = h@U (k-ascending f32 FMA from 0), both chains ----
    float hza = 0.f, hzb = 0.f, hra = 0.f, hrb = 0.f, hna = 0.f, hnb = 0.f;
#define DOTB(uzv, urv, unv, base) \
    { _Pragma("unroll") for (int e = 0; e < 16; e += 2) { \
        const float4 hv = *(const float4*)&hsh2[(base) + e]; \
        hza = __builtin_fmaf(hv.x, uzv[e],   hza); hzb = __builtin_fmaf(hv.y, uzv[e],   hzb); \
        hra = __builtin_fmaf(hv.x, urv[e],   hra); hrb = __builtin_fmaf(hv.y, urv[e],   hrb); \
        hna = __builtin_fmaf(hv.x, unv[e],   hna); hnb = __builtin_fmaf(hv.y, unv[e],   hnb); \
        hza = __builtin_fmaf(hv.z, uzv[e+1], hza); hzb = __builtin_fmaf(hv.w, uzv[e+1], hzb); \
        hra = __builtin_fmaf(hv.z, urv[e+1], hra); hrb = __builtin_fmaf(hv.w, urv[e+1], hrb); \
        hna = __builtin_fmaf(hv.z, unv[e+1], hna); hnb = __builtin_fmaf(hv.w, unv[e+1], hnb); } }
    DOTB(uz0, ur0, un0, 0)
    DOTB(uz1, ur1, un1, 16)
    DOTB(uz2, ur2, un2, 32)
    DOTB(uz3, ur3, un3, 48)
#undef DOTB

    // ---- gates (native f32), r7 expression order ----
    {
      const float tz = hza + b1z, tr = hra + b1r, tn = hna + b1n;
      const float az = axz + tz, ar = axr + tr;
      const float zz = __builtin_amdgcn_rcpf(1.0f + expf(-az));
      const float rr = __builtin_amdgcn_rcpf(1.0f + expf(-ar));
      const float hh = tanhf(axn + (rr * tn));
      ha = (zz * ha) + ((1.0f - zz) * hh);
    }
    {
      const float tz = hzb + b1z, tr = hrb + b1r, tn = hnb + b1n;
      const float az = bxz + tz, ar = bxr + tr;
      const float zz = __builtin_amdgcn_rcpf(1.0f + expf(-az));
      const float rr = __builtin_amdgcn_rcpf(1.0f + expf(-ar));
      const float hh = tanhf(bxn + (rr * tn));
      hb_ = (zz * hb_) + ((1.0f - zz) * hh);
    }

    hsh2[j] = float2{ha, hb_};   // for next step's DOT (single wave: ordered)

    // ---- dense h@Wd: butterfly reduction, no LDS round-trip ----
    // (rounding differs from np sgemm; proven decision-safe r2-vs-r4)
    float pa0 = ha * wd0,  pa1 = ha * wd1;    // chain a logits
    float pb0 = hb_ * wd0, pb1 = hb_ * wd1;   // chain b logits
#pragma unroll
    for (int m = 1; m < 64; m <<= 1) {
      pa0 += __shfl_xor(pa0, m, 64);
      pa1 += __shfl_xor(pa1, m, 64);
      pb0 += __shfl_xor(pb0, m, 64);
      pb1 += __shfl_xor(pb1, m, 64);
    }

    // ---- softmax + gumbel argmax + logP, per chain ----
    int sma, smb;
    {
      const float l0 = pa0 + bd0, l1 = pa1 + bd1;
      const float mxv = fmaxf(l0, l1);
      const float e0 = expf(l0 - mxv), e1 = expf(l1 - mxv);
      const float rs = __builtin_amdgcn_rcpf(e0 + e1);
      const float lp0 = logf(1e-10f + (e0 * rs));
      const float lp1 = logf(1e-10f + (e1 * rs));
      const float g0 = gsh[2*t], g1 = gsh[2*t + 1];
      sma = (lp1 + g1) > (lp0 + g0);
      logPa = logPa + (sma ? lp1 : lp0);
      axz = sma ? xW1z : xW0z;
      axr = sma ? xW1r : xW0r;
      axn = sma ? xW1n : xW0n;
    }
    {
      const float l0 = pb0 + bd0, l1 = pb1 + bd1;
      const float mxv = fmaxf(l0, l1);
      const float e0 = expf(l0 - mxv), e1 = expf(l1 - mxv);
      const float rs = __builtin_amdgcn_rcpf(e0 + e1);
      const float lp0 = logf(1e-10f + (e0 * rs));
      const float lp1 = logf(1e-10f + (e1 * rs));
      const float g0 = gsh[288 + 2*t], g1 = gsh[288 + 2*t + 1];
      smb = (lp1 + g1) > (lp0 + g0);
      logPb = logPb + (smb ? lp1 : lp0);
      bxz = smb ? xW1z : xW0z;
      bxr = smb ? xW1r : xW0r;
      bxn = smb ? xW1n : xW0n;
    }

    if (j == 0) {
      out[(s_base + 0) * NSTEP + t] = sma ? 1.0f : 0.0f;
      out[(s_base + 1) * NSTEP + t] = smb ? 1.0f : 0.0f;
    }
  }

  if (j == 0) {
    *(float2*)&out[NSAMP * NSTEP + s_base] = float2{logPa, logPb};
  }
}

extern "C" void kernel_launch(void* const* d_in, const int* in_sizes, int n_in,
                              void* d_out, int out_size, void* d_ws, size_t ws_size,
                              hipStream_t stream) {
  // inputs (setup_inputs order): nsamples(1), W(2x192), U(64x192), b(2x192),
  // Wd(64x2), bd(2) — float32
  const float* W  = (const float*)d_in[1];
  const float* U  = (const float*)d_in[2];
  const float* B  = (const float*)d_in[3];
  const float* Wd = (const float*)d_in[4];
  const float* Bd = (const float*)d_in[5];
  vmc_kernel<<<dim3(NSAMP / CPB), dim3(HID), 0, stream>>>(W, U, B, Wd, Bd, (float*)d_out);
}

// Round 9
// 813.026 us; speedup vs baseline: 7.2719x; 7.2719x over previous
//
#include <hip/hip_runtime.h>
#include <cstdint>
#include <math.h>

// GREEN since r6. History: r6 1823us (U in alloca-scratch), r7 1783us (CPB=4,
// VGPR capped 256 -> allocator spill, 1 wave/SIMD), r8 5912us (REGRESSION:
// __launch_bounds__(64,2) cut the per-wave budget to 128 arch VGPRs -> U
// spilled to memory scratch: FETCH 4.7GB/dispatch = 2048 waves x 144 steps x
// 16KB re-loads, VALUBusy 5.6%).
// EMPIRICAL RULE: only __launch_bounds__(64,1) gives the 256-VGPR budget that
// keeps U register-resident. At VGPR<=256 the HW allows 2 waves/SIMD anyway
// (2048-reg pool), and grid 2048 blocks = exactly 2/SIMD -> the occupancy r8
// wanted, without the budget cut. This round = r8 kernel + (64,1).
// Locked-in: PRNG = partitionable threefry (key_t = tf((0,42),(0,t)); bits =
// o0^o1 of tf(key_t,(0,2s+cat))); f32 in/out; out = [4096*144][4096]; decisions
// arithmetic-robust (r2/r3/r4 bit-identical; r7/r8 native-f32 absmax 0.0).

#define NSAMP 4096
#define NSTEP 144
#define HID 64
#define CPB 2            // chains per block (one wave)

typedef float v16f __attribute__((ext_vector_type(16)));

// ---- JAX threefry2x32 (20 rounds, key-inject every 4) ----
__device__ __forceinline__ void threefry2x32(uint32_t k0, uint32_t k1,
                                             uint32_t x0, uint32_t x1,
                                             uint32_t& o0, uint32_t& o1) {
  const uint32_t ks0 = k0, ks1 = k1, ks2 = k0 ^ k1 ^ 0x1BD11BDAu;
  x0 += ks0; x1 += ks1;
#define TF_ROUND(d) { x0 += x1; x1 = (x1 << (d)) | (x1 >> (32 - (d))); x1 ^= x0; }
  TF_ROUND(13) TF_ROUND(15) TF_ROUND(26) TF_ROUND(6)
  x0 += ks1; x1 += ks2 + 1u;
  TF_ROUND(17) TF_ROUND(29) TF_ROUND(16) TF_ROUND(24)
  x0 += ks2; x1 += ks0 + 2u;
  TF_ROUND(13) TF_ROUND(15) TF_ROUND(26) TF_ROUND(6)
  x0 += ks0; x1 += ks1 + 3u;
  TF_ROUND(17) TF_ROUND(29) TF_ROUND(16) TF_ROUND(24)
  x0 += ks1; x1 += ks2 + 4u;
  TF_ROUND(13) TF_ROUND(15) TF_ROUND(26) TF_ROUND(6)
  x0 += ks2; x1 += ks0 + 5u;
#undef TF_ROUND
  o0 = x0; o1 = x1;
}

__global__ __launch_bounds__(64, 1) void vmc_kernel(
    const float* __restrict__ W, const float* __restrict__ U,
    const float* __restrict__ B, const float* __restrict__ Wd,
    const float* __restrict__ Bd, float* __restrict__ out) {
#pragma clang fp contract(off)
  const int j = threadIdx.x;           // hidden unit owned by this lane
  const int s_base = blockIdx.x * CPB; // first of 2 chains in this block

  __shared__ __align__(16) float2 hsh2[HID];   // h[unit] = {chain a, chain b}
  __shared__ uint2 kkeys[NSTEP];
  __shared__ float gsh[CPB * 2 * NSTEP];       // gumbels [c*288 + 2t + cat]

  // --- per-step keys: key_t = threefry((0,42),(0,t)) ---
#pragma unroll
  for (int k = 0; k < 3; ++k) {
    const int t = j + 64 * k;
    if (t < NSTEP) {
      uint32_t o0, o1;
      threefry2x32(0u, 42u, 0u, (uint32_t)t, o0, o1);
      kkeys[t].x = o0; kkeys[t].y = o1;
    }
  }
  hsh2[j] = float2{0.0f, 0.0f};
  __syncthreads();

  // --- gumbels: 2 chains x 288 draws; bits = o0^o1 of tf(key_t,(0,2s+cat)) ---
#pragma unroll
  for (int k = 0; k < 9; ++k) {
    const int id = j + 64 * k;              // 0..575 = c*288 + idx
    const int c = id / 288;
    const int idx = id - c * 288;
    const uint2 kt = kkeys[idx >> 1];
    const uint32_t i = 2u * (uint32_t)(s_base + c) + (uint32_t)(idx & 1);
    uint32_t o0, o1;
    threefry2x32(kt.x, kt.y, 0u, i, o0, o1);
    const uint32_t bits = o0 ^ o1;
    union { uint32_t u; float f; } cv; cv.u = (bits >> 9) | 0x3F800000u;
    float uf = cv.f - 1.0f;
    uf = fmaxf(uf, 1.17549435e-38f);
    const float inner = logf(uf);
    gsh[id] = -logf(-inner);
  }
  __syncthreads();

  // --- U columns for unit j, register-resident as named SSA vectors ---
  v16f uz0, uz1, uz2, uz3, ur0, ur1, ur2, ur3, un0, un1, un2, un3;
#define LOADB(v, r, off) \
  { _Pragma("unroll") for (int e = 0; e < 16; ++e) v[e] = U[((r)*16 + e)*192 + (off) + j]; }
  LOADB(uz0, 0, 0)   LOADB(uz1, 1, 0)   LOADB(uz2, 2, 0)   LOADB(uz3, 3, 0)
  LOADB(ur0, 0, 64)  LOADB(ur1, 1, 64)  LOADB(ur2, 2, 64)  LOADB(ur3, 3, 64)
  LOADB(un0, 0, 128) LOADB(un1, 1, 128) LOADB(un2, 2, 128) LOADB(un3, 3, 128)
#undef LOADB

  const float b1z = B[192 + j], b1r = B[256 + j], b1n = B[320 + j];
  const float b0z = B[j],       b0r = B[64 + j],  b0n = B[128 + j];
  const float xW0z = W[j]       + b0z, xW1z = W[192 + j] + b0z;
  const float xW0r = W[64 + j]  + b0r, xW1r = W[256 + j] + b0r;
  const float xW0n = W[128 + j] + b0n, xW1n = W[320 + j] + b0n;
  const float wd0 = Wd[2*j], wd1 = Wd[2*j + 1];
  const float bd0 = Bd[0],   bd1 = Bd[1];

  float ha = 0.0f, hb_ = 0.0f;          // h for chain a / b (unit j)
  float logPa = 0.0f, logPb = 0.0f;
  float axz = b0z, axr = b0r, axn = b0n;  // chain a x-path (t=0: x=0 -> b[0])
  float bxz = b0z, bxr = b0r, bxn = b0n;  // chain b

  for (int t = 0; t < NSTEP; ++t) {
    // ---- hm = h@U (k-ascending f32 FMA from 0), both chains ----
    float hza = 0.f, hzb = 0.f, hra = 0.f, hrb = 0.f, hna = 0.f, hnb = 0.f;
#define DOTB(uzv, urv, unv, base) \
    { _Pragma("unroll") for (int e = 0; e < 16; e += 2) { \
        const float4 hv = *(const float4*)&hsh2[(base) + e]; \
        hza = __builtin_fmaf(hv.x, uzv[e],   hza); hzb = __builtin_fmaf(hv.y, uzv[e],   hzb); \
        hra = __builtin_fmaf(hv.x, urv[e],   hra); hrb = __builtin_fmaf(hv.y, urv[e],   hrb); \
        hna = __builtin_fmaf(hv.x, unv[e],   hna); hnb = __builtin_fmaf(hv.y, unv[e],   hnb); \
        hza = __builtin_fmaf(hv.z, uzv[e+1], hza); hzb = __builtin_fmaf(hv.w, uzv[e+1], hzb); \
        hra = __builtin_fmaf(hv.z, urv[e+1], hra); hrb = __builtin_fmaf(hv.w, urv[e+1], hrb); \
        hna = __builtin_fmaf(hv.z, unv[e+1], hna); hnb = __builtin_fmaf(hv.w, unv[e+1], hnb); } }
    DOTB(uz0, ur0, un0, 0)
    DOTB(uz1, ur1, un1, 16)
    DOTB(uz2, ur2, un2, 32)
    DOTB(uz3, ur3, un3, 48)
#undef DOTB

    // ---- gates (native f32), r7 expression order ----
    {
      const float tz = hza + b1z, tr = hra + b1r, tn = hna + b1n;
      const float az = axz + tz, ar = axr + tr;
      const float zz = __builtin_amdgcn_rcpf(1.0f + expf(-az));
      const float rr = __builtin_amdgcn_rcpf(1.0f + expf(-ar));
      const float hh = tanhf(axn + (rr * tn));
      ha = (zz * ha) + ((1.0f - zz) * hh);
    }
    {
      const float tz = hzb + b1z, tr = hrb + b1r, tn = hnb + b1n;
      const float az = bxz + tz, ar = bxr + tr;
      const float zz = __builtin_amdgcn_rcpf(1.0f + expf(-az));
      const float rr = __builtin_amdgcn_rcpf(1.0f + expf(-ar));
      const float hh = tanhf(bxn + (rr * tn));
      hb_ = (zz * hb_) + ((1.0f - zz) * hh);
    }

    hsh2[j] = float2{ha, hb_};   // for next step's DOT (single wave: ordered)

    // ---- dense h@Wd: butterfly reduction, no LDS round-trip ----
    // (rounding differs from np sgemm; proven decision-safe r2-vs-r4)
    float pa0 = ha * wd0,  pa1 = ha * wd1;    // chain a logits
    float pb0 = hb_ * wd0, pb1 = hb_ * wd1;   // chain b logits
#pragma unroll
    for (int m = 1; m < 64; m <<= 1) {
      pa0 += __shfl_xor(pa0, m, 64);
      pa1 += __shfl_xor(pa1, m, 64);
      pb0 += __shfl_xor(pb0, m, 64);
      pb1 += __shfl_xor(pb1, m, 64);
    }

    // ---- softmax + gumbel argmax + logP, per chain ----
    int sma, smb;
    {
      const float l0 = pa0 + bd0, l1 = pa1 + bd1;
      const float mxv = fmaxf(l0, l1);
      const float e0 = expf(l0 - mxv), e1 = expf(l1 - mxv);
      const float rs = __builtin_amdgcn_rcpf(e0 + e1);
      const float lp0 = logf(1e-10f + (e0 * rs));
      const float lp1 = logf(1e-10f + (e1 * rs));
      const float g0 = gsh[2*t], g1 = gsh[2*t + 1];
      sma = (lp1 + g1) > (lp0 + g0);
      logPa = logPa + (sma ? lp1 : lp0);
      axz = sma ? xW1z : xW0z;
      axr = sma ? xW1r : xW0r;
      axn = sma ? xW1n : xW0n;
    }
    {
      const float l0 = pb0 + bd0, l1 = pb1 + bd1;
      const float mxv = fmaxf(l0, l1);
      const float e0 = expf(l0 - mxv), e1 = expf(l1 - mxv);
      const float rs = __builtin_amdgcn_rcpf(e0 + e1);
      const float lp0 = logf(1e-10f + (e0 * rs));
      const float lp1 = logf(1e-10f + (e1 * rs));
      const float g0 = gsh[288 + 2*t], g1 = gsh[288 + 2*t + 1];
      smb = (lp1 + g1) > (lp0 + g0);
      logPb = logPb + (smb ? lp1 : lp0);
      bxz = smb ? xW1z : xW0z;
      bxr = smb ? xW1r : xW0r;
      bxn = smb ? xW1n : xW0n;
    }

    if (j == 0) {
      out[(s_base + 0) * NSTEP + t] = sma ? 1.0f : 0.0f;
      out[(s_base + 1) * NSTEP + t] = smb ? 1.0f : 0.0f;
    }
  }

  if (j == 0) {
    *(float2*)&out[NSAMP * NSTEP + s_base] = float2{logPa, logPb};
  }
}

extern "C" void kernel_launch(void* const* d_in, const int* in_sizes, int n_in,
                              void* d_out, int out_size, void* d_ws, size_t ws_size,
                              hipStream_t stream) {
  // inputs (setup_inputs order): nsamples(1), W(2x192), U(64x192), b(2x192),
  // Wd(64x2), bd(2) — float32
  const float* W  = (const float*)d_in[1];
  const float* U  = (const float*)d_in[2];
  const float* B  = (const float*)d_in[3];
  const float* Wd = (const float*)d_in[4];
  const float* Bd = (const float*)d_in[5];
  vmc_kernel<<<dim3(NSAMP / CPB), dim3(HID), 0, stream>>>(W, U, B, Wd, Bd, (float*)d_out);
}